// Round 3
// baseline (459.656 us; speedup 1.0000x reference)
//
#include <hip/hip_runtime.h>

#define BDIM 1024
#define PACK_BDIM 256

typedef __attribute__((ext_vector_type(8))) short bf16x8;
typedef __attribute__((ext_vector_type(4))) float f32x4;
typedef __attribute__((ext_vector_type(4))) unsigned int u32x4;

__device__ __forceinline__ unsigned short f2b(float x) {
    unsigned u = __float_as_uint(x);
    return (unsigned short)((u + 0x7fffu + ((u >> 16) & 1u)) >> 16);
}
__device__ __forceinline__ float b2f(unsigned short b) {
    return __uint_as_float(((unsigned)b) << 16);
}

typedef __attribute__((address_space(1))) const unsigned int ga_u32;
typedef __attribute__((address_space(3))) unsigned int la_u32;
__device__ __forceinline__ void gload_lds16(const void* g, void* l) {
    __builtin_amdgcn_global_load_lds((ga_u32*)g, (la_u32*)l, 16, 0, 0);
}

// Pack 9 fp32 128x128 weights into bf16 hi/lo, fragment-direct layout:
// per gemm g: chunk q = (c*8+f)*2+s (c=K-chunk 0..3, f=N-frag 0..7, s=0 hi,1 lo),
// byte addr = g*65536 + q*1024 + lane*16, holding 8 bf16 for
// k = c*32 + (lane>>4)*8 + i, n = f*16 + (lane&15).
__global__ __launch_bounds__(PACK_BDIM) void pack_weights(
    const float* __restrict__ w0, const float* __restrict__ w1,
    const float* __restrict__ w2, const float* __restrict__ w3,
    const float* __restrict__ w4, const float* __restrict__ w5,
    const float* __restrict__ w6, const float* __restrict__ w7,
    const float* __restrict__ w8, unsigned short* __restrict__ wp)
{
    __shared__ float wsm[16384];
    const float* W;
    switch (blockIdx.x) {
        case 0: W = w0; break; case 1: W = w1; break; case 2: W = w2; break;
        case 3: W = w3; break; case 4: W = w4; break; case 5: W = w5; break;
        case 6: W = w6; break; case 7: W = w7; break; default: W = w8; break;
    }
    const int tid = threadIdx.x;
    for (int i = tid; i < 16384; i += PACK_BDIM) wsm[i] = W[i];
    __syncthreads();
    unsigned short* dst = wp + (size_t)blockIdx.x * 32768;
    for (int item = tid; item < 4096; item += PACK_BDIM) {
        const int lane = item & 63, q = item >> 6;
        const int s = q & 1, fc = q >> 1, f = fc & 7, c = fc >> 3;
        const int k0 = c * 32 + (lane >> 4) * 8;
        const int n  = f * 16 + (lane & 15);
        unsigned v2[4];
        for (int i2 = 0; i2 < 4; i2++) {
            unsigned short lohi[2];
            for (int t = 0; t < 2; t++) {
                float x = wsm[(k0 + i2 * 2 + t) * 128 + n];
                unsigned short hb = f2b(x);
                if (s) { hb = f2b(x - b2f(hb)); }
                lohi[t] = hb;
            }
            v2[i2] = (unsigned)lohi[0] | ((unsigned)lohi[1] << 16);
        }
        u32x4 vv; vv[0] = v2[0]; vv[1] = v2[1]; vv[2] = v2[2]; vv[3] = v2[3];
        *(u32x4*)(dst + (size_t)q * 512 + lane * 8) = vv;
    }
}

// Fused dual-input GRU cell. grid = B/128, 1024 thr (16 waves =
// 8 rowgroups x 2 colgroups; each wave: 16 rows x 64 cols = 4 frags).
// Live state per thread <= ~90 VGPR (4-frag sets) -> no scratch spill at
// __launch_bounds__(1024,4) (16 waves/CU). LDS: 64KB weights + 68KB padded
// transpose buffer = 132KB, 1 block/CU.
// gemm ids: 0 ir, 1 iz, 2 in_, 3 sr, 4 sz, 5 sn, 6 hr, 7 hz, 8 hn.
__global__ __launch_bounds__(BDIM, 4) void gru_fused(
    const float* __restrict__ inp, const float* __restrict__ seqp,
    const float* __restrict__ hid, const unsigned short* __restrict__ wp,
    const float* __restrict__ b_ir, const float* __restrict__ b_iz,
    const float* __restrict__ b_in, const float* __restrict__ b_sr,
    const float* __restrict__ b_sz, const float* __restrict__ b_sn,
    const float* __restrict__ b_hr, const float* __restrict__ b_hz,
    const float* __restrict__ b_hn, float* __restrict__ outp)
{
    __shared__ unsigned short wbuf[32768];        // 64 KiB weight stage
    __shared__ __align__(16) float tb[128 * 132]; // 67.6 KiB transpose buffer (pad 132)

    const int tid    = threadIdx.x;
    const int lane   = tid & 63;
    const int wid    = tid >> 6;       // 0..15
    const int rowgrp = wid >> 1;       // 0..7
    const int colgrp = wid & 1;        // 0..1
    const int agrp   = lane >> 4;      // 0..3 (K-group for A/B, row-group for C)
    const int a16    = lane & 15;      // M for A, N for B, col for C
    const int ncol0  = colgrp * 64;
    const size_t row0 = (size_t)blockIdx.x * 128;
    const int locrow_a = rowgrp * 16 + a16;

    const float* pAin  = inp  + (row0 + locrow_a) * 128;
    const float* pAseq = seqp + (row0 + locrow_a) * 128;
    const float* pAhid = hid  + (row0 + locrow_a) * 128;

    f32x4 hx[4], t[4], s1[4], nacc[4], rA[8];
    const f32x4 zv = {0.f, 0.f, 0.f, 0.f};

    auto stage = [&](int g) {
        __syncthreads();                           // prior wbuf readers done
        const char* src = (const char*)wp + (size_t)g * 65536;
        #pragma unroll
        for (int j = 0; j < 4; j++) {
            const int off = (j * 16 + wid) * 1024; // wave-uniform LDS base
            gload_lds16(src + off + lane * 16, (char*)wbuf + off);
        }
        __syncthreads();                           // vmcnt drained before barrier
    };

    // acc (+)= A @ Wg[:, colgrp half]; A fp32 split bf16 hi/lo in-register;
    // W pre-split hi/lo in LDS. 3-term: Ah*Wh + Al*Wh + Ah*Wl.
    auto mm = [&](f32x4* acc, const float* pA, const f32x4* rAv, bool init) {
        if (init) {
            #pragma unroll
            for (int f = 0; f < 4; f++) acc[f] = zv;
        }
        #pragma unroll
        for (int c = 0; c < 4; c++) {
            const float* p = pA + c * 32 + agrp * 8;
            f32x4 x0 = *(const f32x4*)(p);
            f32x4 x1 = *(const f32x4*)(p + 4);
            if (rAv) { x0 *= rAv[2 * c]; x1 *= rAv[2 * c + 1]; }
            bf16x8 ah, al;
            #pragma unroll
            for (int i = 0; i < 4; i++) {
                unsigned short hb = f2b(x0[i]);
                ah[i] = (short)hb;
                al[i] = (short)(__float_as_uint(x0[i] - b2f(hb)) >> 16);
                unsigned short hb1 = f2b(x1[i]);
                ah[4 + i] = (short)hb1;
                al[4 + i] = (short)(__float_as_uint(x1[i] - b2f(hb1)) >> 16);
            }
            #pragma unroll
            for (int f = 0; f < 4; f++) {
                const int fglob = colgrp * 4 + f;
                const bf16x8 wh = *(const bf16x8*)(&wbuf[(size_t)((c * 8 + fglob) * 2 + 0) * 512 + lane * 8]);
                const bf16x8 wl = *(const bf16x8*)(&wbuf[(size_t)((c * 8 + fglob) * 2 + 1) * 512 + lane * 8]);
                acc[f] = __builtin_amdgcn_mfma_f32_16x16x32_bf16(ah, wh, acc[f], 0, 0, 0);
                acc[f] = __builtin_amdgcn_mfma_f32_16x16x32_bf16(al, wh, acc[f], 0, 0, 0);
                acc[f] = __builtin_amdgcn_mfma_f32_16x16x32_bf16(ah, wl, acc[f], 0, 0, 0);
            }
        }
    };

    auto addb = [&](f32x4* acc, const float* b) {
        #pragma unroll
        for (int f = 0; f < 4; f++) {
            float bv = b[ncol0 + f * 16 + a16];
            #pragma unroll
            for (int j = 0; j < 4; j++) acc[f][j] += bv;
        }
    };

    auto sigm = [](float x) { return 1.f / (1.f + __expf(-x)); };
    auto tanh_ = [](float x) {
        x = fminf(18.f, fmaxf(-18.f, x));
        float e = __expf(2.f * x);
        return (e - 1.f) / (e + 1.f);
    };

    // ---------- r gate ----------
    stage(6);
    mm(hx, pAhid, nullptr, true); addb(hx, b_hr);        // hr (shared)
    stage(0);
    mm(t, pAin, nullptr, true);  addb(t, b_ir);
    #pragma unroll
    for (int f = 0; f < 4; f++)
        #pragma unroll
        for (int j = 0; j < 4; j++) s1[f][j] = sigm(t[f][j] + hx[f][j]);   // r_input
    stage(3);
    mm(t, pAseq, nullptr, true); addb(t, b_sr);
    #pragma unroll
    for (int f = 0; f < 4; f++)
        #pragma unroll
        for (int j = 0; j < 4; j++) {
            int row = rowgrp * 16 + agrp * 4 + j;        // C-layout local row
            int col = ncol0 + f * 16 + a16;
            tb[row * 132 + col] = 0.5f * (s1[f][j] + sigm(t[f][j] + hx[f][j]));
        }
    __syncthreads();
    #pragma unroll
    for (int c = 0; c < 4; c++) {                        // r -> A-layout regs
        int rk = c * 32 + agrp * 8;
        rA[2 * c]     = *(const f32x4*)(&tb[locrow_a * 132 + rk]);
        rA[2 * c + 1] = *(const f32x4*)(&tb[locrow_a * 132 + rk + 4]);
    }

    // ---------- n (kept in registers through z phase) ----------
    stage(2);
    mm(nacc, pAin, nullptr, true);  addb(nacc, b_in);
    stage(5);
    mm(nacc, pAseq, nullptr, false); addb(nacc, b_sn);
    stage(8);
    mm(nacc, pAhid, rA, false); addb(nacc, b_hn);        // (r*hidden) @ W_hn

    // ---------- z gate ----------
    stage(7);
    mm(hx, pAhid, nullptr, true); addb(hx, b_hz);        // hz (shared)
    stage(1);
    mm(t, pAin, nullptr, true);  addb(t, b_iz);
    #pragma unroll
    for (int f = 0; f < 4; f++)
        #pragma unroll
        for (int j = 0; j < 4; j++) s1[f][j] = sigm(t[f][j] + hx[f][j]);   // z_input
    stage(4);
    mm(t, pAseq, nullptr, true); addb(t, b_sz);

    // ---------- blend in frag space, transpose, coalesced store ----------
    #pragma unroll
    for (int f = 0; f < 4; f++)
        #pragma unroll
        for (int j = 0; j < 4; j++) {
            int row = rowgrp * 16 + agrp * 4 + j;
            int col = ncol0 + f * 16 + a16;
            float zz = 0.5f * (s1[f][j] + sigm(t[f][j] + hx[f][j]));
            float h  = hid[(row0 + row) * 128 + col];    // frag-direct, L2-warm
            float nn = tanh_(nacc[f][j]);
            tb[row * 132 + col] = (1.f - zz) * nn + zz * h;
        }
    __syncthreads();
    #pragma unroll
    for (int p = 0; p < 4; p++) {
        int e = p * 4096 + tid * 4;
        int rrow = e >> 7, c0 = e & 127;
        f32x4 v = *(const f32x4*)(&tb[rrow * 132 + c0]);
        *(f32x4*)(&outp[(row0 + rrow) * 128 + c0]) = v;
    }
}

extern "C" void kernel_launch(void* const* d_in, const int* in_sizes, int n_in,
                              void* d_out, int out_size, void* d_ws, size_t ws_size,
                              hipStream_t stream)
{
    (void)in_sizes; (void)n_in; (void)out_size; (void)ws_size;
    const float* inp  = (const float*)d_in[0];
    const float* seqp = (const float*)d_in[1];
    const float* hid  = (const float*)d_in[2];
    const float* W[9]; const float* Bv[9];
    for (int i = 0; i < 9; i++) {
        W[i]  = (const float*)d_in[3 + 2 * i];
        Bv[i] = (const float*)d_in[4 + 2 * i];
    }
    unsigned short* wp = (unsigned short*)d_ws; // needs 589,824 B

    pack_weights<<<9, PACK_BDIM, 0, stream>>>(W[0], W[1], W[2], W[3], W[4],
                                              W[5], W[6], W[7], W[8], wp);
    gru_fused<<<1024, BDIM, 0, stream>>>(inp, seqp, hid, wp,
                                         Bv[0], Bv[1], Bv[2], Bv[3], Bv[4],
                                         Bv[5], Bv[6], Bv[7], Bv[8],
                                         (float*)d_out);
}

// Round 4
// 317.731 us; speedup vs baseline: 1.4467x; 1.4467x over previous
//
#include <hip/hip_runtime.h>

#define BDIM 512
#define PACK_BDIM 256

typedef __attribute__((ext_vector_type(8))) short bf16x8;
typedef __attribute__((ext_vector_type(4))) float f32x4;
typedef __attribute__((ext_vector_type(4))) unsigned int u32x4;

__device__ __forceinline__ unsigned short f2b(float x) {
    unsigned u = __float_as_uint(x);
    return (unsigned short)((u + 0x7fffu + ((u >> 16) & 1u)) >> 16);
}
__device__ __forceinline__ float b2f(unsigned short b) {
    return __uint_as_float(((unsigned)b) << 16);
}

typedef __attribute__((address_space(1))) const unsigned int ga_u32;
typedef __attribute__((address_space(3))) unsigned int la_u32;
__device__ __forceinline__ void gload_lds16(const void* g, void* l) {
    __builtin_amdgcn_global_load_lds((ga_u32*)g, (la_u32*)l, 16, 0, 0);
}

// Pack 9 fp32 128x128 weights into bf16 hi/lo, SEPARATED hi/lo blocks:
// per gemm g (65536 B): s=0 hi block (32 KB), s=1 lo block (32 KB);
// within block: chunk cf = c*8+f (1 KB each), byte = lane*16, holding 8 bf16
// for k = c*32 + (lane>>4)*8 + i, n = f*16 + (lane&15).
__global__ __launch_bounds__(PACK_BDIM) void pack_weights(
    const float* __restrict__ w0, const float* __restrict__ w1,
    const float* __restrict__ w2, const float* __restrict__ w3,
    const float* __restrict__ w4, const float* __restrict__ w5,
    const float* __restrict__ w6, const float* __restrict__ w7,
    const float* __restrict__ w8, unsigned short* __restrict__ wp)
{
    __shared__ float wsm[16384];
    const float* W;
    switch (blockIdx.x) {
        case 0: W = w0; break; case 1: W = w1; break; case 2: W = w2; break;
        case 3: W = w3; break; case 4: W = w4; break; case 5: W = w5; break;
        case 6: W = w6; break; case 7: W = w7; break; default: W = w8; break;
    }
    const int tid = threadIdx.x;
    for (int i = tid; i < 16384; i += PACK_BDIM) wsm[i] = W[i];
    __syncthreads();
    unsigned short* dst = wp + (size_t)blockIdx.x * 32768;
    for (int item = tid; item < 4096; item += PACK_BDIM) {
        const int lane = item & 63, q = item >> 6;     // q = s*32 + c*8 + f
        const int s = q >> 5, cf = q & 31, c = cf >> 3, f = cf & 7;
        const int k0 = c * 32 + (lane >> 4) * 8;
        const int n  = f * 16 + (lane & 15);
        unsigned v2[4];
        for (int i2 = 0; i2 < 4; i2++) {
            unsigned short lohi[2];
            for (int t = 0; t < 2; t++) {
                float x = wsm[(k0 + i2 * 2 + t) * 128 + n];
                unsigned short hb = f2b(x);
                if (s) { hb = (unsigned short)(__float_as_uint(x - b2f(hb)) >> 16); }
                lohi[t] = hb;
            }
            v2[i2] = (unsigned)lohi[0] | ((unsigned)lohi[1] << 16);
        }
        u32x4 vv; vv[0] = v2[0]; vv[1] = v2[1]; vv[2] = v2[2]; vv[3] = v2[3];
        *(u32x4*)(dst + (size_t)(s * 32 + cf) * 512 + lane * 8) = vv;
    }
}

// Fused dual-input GRU cell. grid = B/64, 512 thr (8 waves = 4 rowgrp x 2 colgrp;
// each wave 16 rows x 64 cols = 4 frags/set). LDS = 32KB weight sub-stage +
// 33KB padded transpose buffer = 66.5KB -> 2 blocks/CU at VGPR<=128
// (__launch_bounds__(512,2): observed hipcc semantics = min BLOCKS/CU -> cap
// 2048/16waves = 128 VGPR, R1-proven no-spill allocation).
// Each phase: [stage Wh | load+split A] sync [hi-MFMAs] sync [stage Wl] sync
// [lo-MFMAs]; the two co-resident blocks overlap each other's drains.
// gemm ids: 0 ir, 1 iz, 2 in_, 3 sr, 4 sz, 5 sn, 6 hr, 7 hz, 8 hn.
__global__ __launch_bounds__(BDIM, 2) void gru_fused(
    const float* __restrict__ inp, const float* __restrict__ seqp,
    const float* __restrict__ hid, const unsigned short* __restrict__ wp,
    const float* __restrict__ b_ir, const float* __restrict__ b_iz,
    const float* __restrict__ b_in, const float* __restrict__ b_sr,
    const float* __restrict__ b_sz, const float* __restrict__ b_sn,
    const float* __restrict__ b_hr, const float* __restrict__ b_hz,
    const float* __restrict__ b_hn, float* __restrict__ outp)
{
    __shared__ unsigned short whbuf[16384];       // 32 KiB: current hi- or lo-weight sub-stage
    __shared__ __align__(16) float rbuf[64 * 132]; // 33 KiB: r / output transpose (pad 132)

    const int tid    = threadIdx.x;
    const int lane   = tid & 63;
    const int wid    = tid >> 6;       // 0..7
    const int rowgrp = wid >> 1;       // 0..3
    const int colgrp = wid & 1;        // 0..1
    const int agrp   = lane >> 4;      // 0..3 (K-group for A/B, row-group for C)
    const int a16    = lane & 15;      // M for A, N for B, col for C
    const int ncol0  = colgrp * 64;
    const size_t row0 = (size_t)blockIdx.x * 64;
    const int locrow_a = rowgrp * 16 + a16;

    const float* pAin  = inp  + (row0 + locrow_a) * 128;
    const float* pAseq = seqp + (row0 + locrow_a) * 128;
    const float* pAhid = hid  + (row0 + locrow_a) * 128;

    f32x4 hx[4], t[4], s1[4], nacc[4];
    const f32x4 zv = {0.f, 0.f, 0.f, 0.f};

    auto stage = [&](int g, int s) {   // 32 KB sub-stage, caller handles barriers
        const char* src = (const char*)wp + (size_t)g * 65536 + (size_t)s * 32768;
        #pragma unroll
        for (int j = 0; j < 4; j++) {
            const int off = (j * 8 + wid) * 1024;  // wave-uniform LDS base
            gload_lds16(src + off + lane * 16, (char*)whbuf + off);
        }
    };

    // One GEMM phase: acc (+)= A @ Wg[:, colgrp half], 3-term bf16 split.
    auto phase = [&](int g, f32x4* acc, const float* pA, bool withR, bool init) {
        __syncthreads();                       // prior whbuf readers done
        stage(g, 0);                           // Wh in flight
        bf16x8 ah[4], al[4];
        #pragma unroll
        for (int c = 0; c < 4; c++) {          // load + split A under the staging
            const float* p = pA + c * 32 + agrp * 8;
            f32x4 x0 = *(const f32x4*)(p);
            f32x4 x1 = *(const f32x4*)(p + 4);
            if (withR) {
                const int rk = c * 32 + agrp * 8;
                x0 *= *(const f32x4*)(&rbuf[locrow_a * 132 + rk]);
                x1 *= *(const f32x4*)(&rbuf[locrow_a * 132 + rk + 4]);
            }
            #pragma unroll
            for (int i = 0; i < 4; i++) {
                unsigned short hb = f2b(x0[i]);
                ah[c][i] = (short)hb;
                al[c][i] = (short)(__float_as_uint(x0[i] - b2f(hb)) >> 16);
                unsigned short hb1 = f2b(x1[i]);
                ah[c][4 + i] = (short)hb1;
                al[c][4 + i] = (short)(__float_as_uint(x1[i] - b2f(hb1)) >> 16);
            }
        }
        if (init) {
            #pragma unroll
            for (int f = 0; f < 4; f++) acc[f] = zv;
        }
        __syncthreads();                       // Wh drained (vmcnt before barrier)
        #pragma unroll
        for (int c = 0; c < 4; c++)
            #pragma unroll
            for (int f = 0; f < 4; f++) {
                const int fglob = colgrp * 4 + f;
                const bf16x8 wh = *(const bf16x8*)(&whbuf[(size_t)(c * 8 + fglob) * 512 + lane * 8]);
                acc[f] = __builtin_amdgcn_mfma_f32_16x16x32_bf16(ah[c], wh, acc[f], 0, 0, 0);
                acc[f] = __builtin_amdgcn_mfma_f32_16x16x32_bf16(al[c], wh, acc[f], 0, 0, 0);
            }
        __syncthreads();                       // Wh readers done
        stage(g, 1);                           // Wl in flight
        __syncthreads();                       // Wl drained
        #pragma unroll
        for (int c = 0; c < 4; c++)
            #pragma unroll
            for (int f = 0; f < 4; f++) {
                const int fglob = colgrp * 4 + f;
                const bf16x8 wl = *(const bf16x8*)(&whbuf[(size_t)(c * 8 + fglob) * 512 + lane * 8]);
                acc[f] = __builtin_amdgcn_mfma_f32_16x16x32_bf16(ah[c], wl, acc[f], 0, 0, 0);
            }
    };

    auto addb = [&](f32x4* acc, const float* b) {
        #pragma unroll
        for (int f = 0; f < 4; f++) {
            float bv = b[ncol0 + f * 16 + a16];
            #pragma unroll
            for (int j = 0; j < 4; j++) acc[f][j] += bv;
        }
    };

    auto sigm = [](float x) { return 1.f / (1.f + __expf(-x)); };
    auto tanh_ = [](float x) {
        x = fminf(18.f, fmaxf(-18.f, x));
        float e = __expf(2.f * x);
        return (e - 1.f) / (e + 1.f);
    };

    // ---------- r gate ----------
    phase(6, hx, pAhid, false, true); addb(hx, b_hr);    // hr (shared by both r halves)
    phase(0, t, pAin, false, true);  addb(t, b_ir);
    #pragma unroll
    for (int f = 0; f < 4; f++)
        #pragma unroll
        for (int j = 0; j < 4; j++) s1[f][j] = sigm(t[f][j] + hx[f][j]);   // r_input
    phase(3, t, pAseq, false, true); addb(t, b_sr);
    #pragma unroll
    for (int f = 0; f < 4; f++)
        #pragma unroll
        for (int j = 0; j < 4; j++) {
            int row = rowgrp * 16 + agrp * 4 + j;        // C-layout local row
            int col = ncol0 + f * 16 + a16;
            rbuf[row * 132 + col] = 0.5f * (s1[f][j] + sigm(t[f][j] + hx[f][j]));
        }
    // next phase's leading __syncthreads makes r visible before any reader

    // ---------- n (stays in registers to the end) ----------
    phase(2, nacc, pAin, false, true);  addb(nacc, b_in);
    phase(5, nacc, pAseq, false, false); addb(nacc, b_sn);
    phase(8, nacc, pAhid, true, false);  addb(nacc, b_hn);   // (r*hidden) @ W_hn

    // ---------- z gate ----------
    phase(7, hx, pAhid, false, true); addb(hx, b_hz);    // hz (shared by both z halves)
    phase(1, t, pAin, false, true);  addb(t, b_iz);
    #pragma unroll
    for (int f = 0; f < 4; f++)
        #pragma unroll
        for (int j = 0; j < 4; j++) s1[f][j] = sigm(t[f][j] + hx[f][j]);   // z_input
    phase(4, t, pAseq, false, true); addb(t, b_sz);

    // ---------- blend in frag space -> rbuf -> coalesced store ----------
    #pragma unroll
    for (int f = 0; f < 4; f++)
        #pragma unroll
        for (int j = 0; j < 4; j++) {
            int row = rowgrp * 16 + agrp * 4 + j;
            int col = ncol0 + f * 16 + a16;
            float zz = 0.5f * (s1[f][j] + sigm(t[f][j] + hx[f][j]));
            float h  = hid[(row0 + row) * 128 + col];    // frag-direct, L2-warm
            float nn = tanh_(nacc[f][j]);
            rbuf[row * 132 + col] = (1.f - zz) * nn + zz * h;
        }
    __syncthreads();
    #pragma unroll
    for (int p = 0; p < 4; p++) {
        int e = p * 2048 + tid * 4;
        int rrow = e >> 7, c0 = e & 127;
        f32x4 v = *(const f32x4*)(&rbuf[rrow * 132 + c0]);
        *(f32x4*)(&outp[(row0 + rrow) * 128 + c0]) = v;
    }
}

extern "C" void kernel_launch(void* const* d_in, const int* in_sizes, int n_in,
                              void* d_out, int out_size, void* d_ws, size_t ws_size,
                              hipStream_t stream)
{
    (void)in_sizes; (void)n_in; (void)out_size; (void)ws_size;
    const float* inp  = (const float*)d_in[0];
    const float* seqp = (const float*)d_in[1];
    const float* hid  = (const float*)d_in[2];
    const float* W[9]; const float* Bv[9];
    for (int i = 0; i < 9; i++) {
        W[i]  = (const float*)d_in[3 + 2 * i];
        Bv[i] = (const float*)d_in[4 + 2 * i];
    }
    unsigned short* wp = (unsigned short*)d_ws; // needs 589,824 B

    pack_weights<<<9, PACK_BDIM, 0, stream>>>(W[0], W[1], W[2], W[3], W[4],
                                              W[5], W[6], W[7], W[8], wp);
    gru_fused<<<2048, BDIM, 0, stream>>>(inp, seqp, hid, wp,
                                         Bv[0], Bv[1], Bv[2], Bv[3], Bv[4],
                                         Bv[5], Bv[6], Bv[7], Bv[8],
                                         (float*)d_out);
}

// Round 5
// 312.050 us; speedup vs baseline: 1.4730x; 1.0182x over previous
//
#include <hip/hip_runtime.h>

#define BDIM 512
#define PACK_BDIM 256

typedef __attribute__((ext_vector_type(8))) short bf16x8;
typedef __attribute__((ext_vector_type(4))) float f32x4;
typedef __attribute__((ext_vector_type(4))) unsigned int u32x4;

__device__ __forceinline__ unsigned short f2b(float x) {
    unsigned u = __float_as_uint(x);
    return (unsigned short)((u + 0x7fffu + ((u >> 16) & 1u)) >> 16);
}
__device__ __forceinline__ float b2f(unsigned short b) {
    return __uint_as_float(((unsigned)b) << 16);
}

typedef __attribute__((address_space(1))) const unsigned int ga_u32;
typedef __attribute__((address_space(3))) unsigned int la_u32;
__device__ __forceinline__ void gload_lds16(const void* g, void* l) {
    __builtin_amdgcn_global_load_lds((ga_u32*)g, (la_u32*)l, 16, 0, 0);
}

// Pack 9 fp32 128x128 weights into bf16 hi/lo, SEPARATED hi/lo blocks:
// per gemm g (65536 B): s=0 hi block (32 KB), s=1 lo block (32 KB);
// within block: chunk cf = c*8+f (1 KB each), byte = lane*16, holding 8 bf16
// for k = c*32 + (lane>>4)*8 + i, n = f*16 + (lane&15).
__global__ __launch_bounds__(PACK_BDIM) void pack_weights(
    const float* __restrict__ w0, const float* __restrict__ w1,
    const float* __restrict__ w2, const float* __restrict__ w3,
    const float* __restrict__ w4, const float* __restrict__ w5,
    const float* __restrict__ w6, const float* __restrict__ w7,
    const float* __restrict__ w8, unsigned short* __restrict__ wp)
{
    __shared__ float wsm[16384];
    const float* W;
    switch (blockIdx.x) {
        case 0: W = w0; break; case 1: W = w1; break; case 2: W = w2; break;
        case 3: W = w3; break; case 4: W = w4; break; case 5: W = w5; break;
        case 6: W = w6; break; case 7: W = w7; break; default: W = w8; break;
    }
    const int tid = threadIdx.x;
    for (int i = tid; i < 16384; i += PACK_BDIM) wsm[i] = W[i];
    __syncthreads();
    unsigned short* dst = wp + (size_t)blockIdx.x * 32768;
    for (int item = tid; item < 4096; item += PACK_BDIM) {
        const int lane = item & 63, q = item >> 6;     // q = s*32 + c*8 + f
        const int s = q >> 5, cf = q & 31, c = cf >> 3, f = cf & 7;
        const int k0 = c * 32 + (lane >> 4) * 8;
        const int n  = f * 16 + (lane & 15);
        unsigned v2[4];
        for (int i2 = 0; i2 < 4; i2++) {
            unsigned short lohi[2];
            for (int t = 0; t < 2; t++) {
                float x = wsm[(k0 + i2 * 2 + t) * 128 + n];
                unsigned short hb = f2b(x);
                if (s) { hb = (unsigned short)(__float_as_uint(x - b2f(hb)) >> 16); }
                lohi[t] = hb;
            }
            v2[i2] = (unsigned)lohi[0] | ((unsigned)lohi[1] << 16);
        }
        u32x4 vv; vv[0] = v2[0]; vv[1] = v2[1]; vv[2] = v2[2]; vv[3] = v2[3];
        *(u32x4*)(dst + (size_t)(s * 32 + cf) * 512 + lane * 8) = vv;
    }
}

// Fused dual-input GRU cell. grid = B/64, 512 thr (8 waves = 4 rowgrp x 2 colgrp;
// each wave 16 rows x 64 cols, 4 frags/set). LDS = EXACTLY 32768 B (usable
// per-CU LDS pool measured at 131072 B across R2/R4: 2x65536 fit, 2x66560
// did not) -> residency bound by VGPR: ~110 VGPR -> 4 waves/SIMD -> 2
// blocks/CU co-resident, their barrier drains mutually overlapped.
// whbuf is time-shared: weight sub-stages (32KB) / r transpose / out transpose
// (fp32 64x128 XOR-swizzled col^((row&7)<<3), R1-proven).
// r lives in rA[8] registers for exactly one phase (hn scheduled first in n).
// gemm ids: 0 ir, 1 iz, 2 in_, 3 sr, 4 sz, 5 sn, 6 hr, 7 hz, 8 hn.
__global__ __launch_bounds__(BDIM, 2) void gru_fused(
    const float* __restrict__ inp, const float* __restrict__ seqp,
    const float* __restrict__ hid, const unsigned short* __restrict__ wp,
    const float* __restrict__ b_ir, const float* __restrict__ b_iz,
    const float* __restrict__ b_in, const float* __restrict__ b_sr,
    const float* __restrict__ b_sz, const float* __restrict__ b_sn,
    const float* __restrict__ b_hr, const float* __restrict__ b_hz,
    const float* __restrict__ b_hn, float* __restrict__ outp)
{
    __shared__ __align__(16) unsigned short whbuf[16384]; // 32 KiB, time-shared
    float* tb = (float*)whbuf;

    const int tid    = threadIdx.x;
    const int lane   = tid & 63;
    const int wid    = tid >> 6;       // 0..7
    const int rowgrp = wid >> 1;       // 0..3
    const int colgrp = wid & 1;        // 0..1
    const int agrp   = lane >> 4;      // 0..3 (K-group for A/B, row-group for C)
    const int a16    = lane & 15;      // M for A, N for B, col for C
    const int ncol0  = colgrp * 64;
    const size_t row0 = (size_t)blockIdx.x * 64;
    const int locrow_a = rowgrp * 16 + a16;
    const int rswA = (locrow_a & 7) << 3;

    const float* pAin  = inp  + (row0 + locrow_a) * 128;
    const float* pAseq = seqp + (row0 + locrow_a) * 128;
    const float* pAhid = hid  + (row0 + locrow_a) * 128;

    f32x4 hx[4], t[4], s1[4], nacc[4], rA[8];
    const f32x4 zv = {0.f, 0.f, 0.f, 0.f};

    auto stage = [&](int g, int s) {   // 32 KB sub-stage, caller handles barriers
        const char* src = (const char*)wp + (size_t)g * 65536 + (size_t)s * 32768;
        #pragma unroll
        for (int j = 0; j < 4; j++) {
            const int off = (j * 8 + wid) * 1024;  // wave-uniform LDS base
            gload_lds16(src + off + lane * 16, (char*)whbuf + off);
        }
    };

    // One GEMM phase: acc (+)= A @ Wg[:, colgrp half], 3-term bf16 split.
    auto phase = [&](int g, f32x4* acc, const float* pA, const f32x4* rAv, bool init) {
        __syncthreads();                       // prior whbuf readers done
        stage(g, 0);                           // Wh in flight
        bf16x8 ah[4], al[4];
        #pragma unroll
        for (int c = 0; c < 4; c++) {          // load + split A under the staging
            const float* p = pA + c * 32 + agrp * 8;
            f32x4 x0 = *(const f32x4*)(p);
            f32x4 x1 = *(const f32x4*)(p + 4);
            if (rAv) { x0 *= rAv[2 * c]; x1 *= rAv[2 * c + 1]; }
            #pragma unroll
            for (int i = 0; i < 4; i++) {
                unsigned short hb = f2b(x0[i]);
                ah[c][i] = (short)hb;
                al[c][i] = (short)(__float_as_uint(x0[i] - b2f(hb)) >> 16);
                unsigned short hb1 = f2b(x1[i]);
                ah[c][4 + i] = (short)hb1;
                al[c][4 + i] = (short)(__float_as_uint(x1[i] - b2f(hb1)) >> 16);
            }
        }
        if (init) {
            #pragma unroll
            for (int f = 0; f < 4; f++) acc[f] = zv;
        }
        __syncthreads();                       // Wh drained (vmcnt before barrier)
        #pragma unroll
        for (int c = 0; c < 4; c++)
            #pragma unroll
            for (int f = 0; f < 4; f++) {
                const int fglob = colgrp * 4 + f;
                const bf16x8 wh = *(const bf16x8*)(&whbuf[(size_t)(c * 8 + fglob) * 512 + lane * 8]);
                acc[f] = __builtin_amdgcn_mfma_f32_16x16x32_bf16(ah[c], wh, acc[f], 0, 0, 0);
                acc[f] = __builtin_amdgcn_mfma_f32_16x16x32_bf16(al[c], wh, acc[f], 0, 0, 0);
            }
        __syncthreads();                       // Wh readers done
        stage(g, 1);                           // Wl in flight
        __syncthreads();                       // Wl drained
        #pragma unroll
        for (int c = 0; c < 4; c++)
            #pragma unroll
            for (int f = 0; f < 4; f++) {
                const int fglob = colgrp * 4 + f;
                const bf16x8 wl = *(const bf16x8*)(&whbuf[(size_t)(c * 8 + fglob) * 512 + lane * 8]);
                acc[f] = __builtin_amdgcn_mfma_f32_16x16x32_bf16(ah[c], wl, acc[f], 0, 0, 0);
            }
    };

    auto addb = [&](f32x4* acc, const float* b) {
        #pragma unroll
        for (int f = 0; f < 4; f++) {
            float bv = b[ncol0 + f * 16 + a16];
            #pragma unroll
            for (int j = 0; j < 4; j++) acc[f][j] += bv;
        }
    };

    auto sigm = [](float x) { return 1.f / (1.f + __expf(-x)); };
    auto tanh_ = [](float x) {
        x = fminf(18.f, fmaxf(-18.f, x));
        float e = __expf(2.f * x);
        return (e - 1.f) / (e + 1.f);
    };

    // ---------- r gate ----------
    phase(6, hx, pAhid, nullptr, true); addb(hx, b_hr);    // hr (shared by both r halves)
    phase(0, t, pAin, nullptr, true);  addb(t, b_ir);
    #pragma unroll
    for (int f = 0; f < 4; f++)
        #pragma unroll
        for (int j = 0; j < 4; j++) s1[f][j] = sigm(t[f][j] + hx[f][j]);   // r_input
    phase(3, t, pAseq, nullptr, true); addb(t, b_sr);

    // ---------- r transpose through whbuf, into rA registers ----------
    __syncthreads();                                       // phase(3) Wl readers done
    #pragma unroll
    for (int f = 0; f < 4; f++)
        #pragma unroll
        for (int j = 0; j < 4; j++) {
            int row = rowgrp * 16 + agrp * 4 + j;          // C-layout local row
            int col = ncol0 + f * 16 + a16;
            tb[row * 128 + (col ^ ((row & 7) << 3))] =
                0.5f * (s1[f][j] + sigm(t[f][j] + hx[f][j]));
        }
    __syncthreads();
    #pragma unroll
    for (int c = 0; c < 4; c++) {                          // r -> A-layout regs
        int rk = (c * 32 + agrp * 8) ^ rswA;
        rA[2 * c]     = *(const f32x4*)(&tb[locrow_a * 128 + rk]);
        rA[2 * c + 1] = *(const f32x4*)(&tb[locrow_a * 128 + rk + 4]);
    }
    // phase(8)'s leading __syncthreads (lgkmcnt+vmcnt drain) protects these
    // ds_reads from the upcoming stage() overwrite.

    // ---------- n: hn FIRST (rA dies immediately), then in_, sn ----------
    phase(8, nacc, pAhid, rA, true);      addb(nacc, b_hn);   // (r*hidden) @ W_hn
    phase(2, nacc, pAin, nullptr, false);  addb(nacc, b_in);
    phase(5, nacc, pAseq, nullptr, false); addb(nacc, b_sn);

    // ---------- z gate ----------
    phase(7, hx, pAhid, nullptr, true); addb(hx, b_hz);    // hz (shared by both z halves)
    phase(1, t, pAin, nullptr, true);  addb(t, b_iz);
    #pragma unroll
    for (int f = 0; f < 4; f++)
        #pragma unroll
        for (int j = 0; j < 4; j++) s1[f][j] = sigm(t[f][j] + hx[f][j]);   // z_input
    phase(4, t, pAseq, nullptr, true); addb(t, b_sz);

    // ---------- blend in frag space -> whbuf -> coalesced store ----------
    __syncthreads();                                       // phase(4) Wl readers done
    #pragma unroll
    for (int f = 0; f < 4; f++)
        #pragma unroll
        for (int j = 0; j < 4; j++) {
            int row = rowgrp * 16 + agrp * 4 + j;
            int col = ncol0 + f * 16 + a16;
            float zz = 0.5f * (s1[f][j] + sigm(t[f][j] + hx[f][j]));
            float h  = hid[(row0 + row) * 128 + col];      // frag-direct, L2-warm
            float nn = tanh_(nacc[f][j]);
            tb[row * 128 + (col ^ ((row & 7) << 3))] = (1.f - zz) * nn + zz * h;
        }
    __syncthreads();
    #pragma unroll
    for (int p = 0; p < 4; p++) {
        int e = p * 2048 + tid * 4;
        int rrow = e >> 7, c0 = e & 127;
        f32x4 v = *(const f32x4*)(&tb[rrow * 128 + (c0 ^ ((rrow & 7) << 3))]);
        *(f32x4*)(&outp[(row0 + rrow) * 128 + c0]) = v;
    }
}

extern "C" void kernel_launch(void* const* d_in, const int* in_sizes, int n_in,
                              void* d_out, int out_size, void* d_ws, size_t ws_size,
                              hipStream_t stream)
{
    (void)in_sizes; (void)n_in; (void)out_size; (void)ws_size;
    const float* inp  = (const float*)d_in[0];
    const float* seqp = (const float*)d_in[1];
    const float* hid  = (const float*)d_in[2];
    const float* W[9]; const float* Bv[9];
    for (int i = 0; i < 9; i++) {
        W[i]  = (const float*)d_in[3 + 2 * i];
        Bv[i] = (const float*)d_in[4 + 2 * i];
    }
    unsigned short* wp = (unsigned short*)d_ws; // needs 589,824 B

    pack_weights<<<9, PACK_BDIM, 0, stream>>>(W[0], W[1], W[2], W[3], W[4],
                                              W[5], W[6], W[7], W[8], wp);
    gru_fused<<<2048, BDIM, 0, stream>>>(inp, seqp, hid, wp,
                                         Bv[0], Bv[1], Bv[2], Bv[3], Bv[4],
                                         Bv[5], Bv[6], Bv[7], Bv[8],
                                         (float*)d_out);
}

// Round 7
// 291.805 us; speedup vs baseline: 1.5752x; 1.0694x over previous
//
#include <hip/hip_runtime.h>

#define BDIM 512
#define PACK_BDIM 256

typedef __attribute__((ext_vector_type(8))) short bf16x8;
typedef __attribute__((ext_vector_type(4))) float f32x4;
typedef __attribute__((ext_vector_type(4))) unsigned int u32x4;

__device__ __forceinline__ unsigned short f2b(float x) {
    unsigned u = __float_as_uint(x);
    return (unsigned short)((u + 0x7fffu + ((u >> 16) & 1u)) >> 16);
}
__device__ __forceinline__ float b2f(unsigned short b) {
    return __uint_as_float(((unsigned)b) << 16);
}

typedef __attribute__((address_space(1))) const unsigned int ga_u32;
typedef __attribute__((address_space(3))) unsigned int la_u32;
__device__ __forceinline__ void gload_lds16(const void* g, void* l) {
    __builtin_amdgcn_global_load_lds((ga_u32*)g, (la_u32*)l, 16, 0, 0);
}

// Pack 9 fp32 128x128 weights into bf16 hi/lo, SEPARATED hi/lo blocks:
// per gemm g (65536 B): s=0 hi block (32 KB), s=1 lo block (32 KB);
// within block: chunk cf = c*8+f (1 KB each), byte = lane*16, holding 8 bf16
// for k = c*32 + (lane>>4)*8 + i, n = f*16 + (lane&15).
__global__ __launch_bounds__(PACK_BDIM) void pack_weights(
    const float* __restrict__ w0, const float* __restrict__ w1,
    const float* __restrict__ w2, const float* __restrict__ w3,
    const float* __restrict__ w4, const float* __restrict__ w5,
    const float* __restrict__ w6, const float* __restrict__ w7,
    const float* __restrict__ w8, unsigned short* __restrict__ wp)
{
    __shared__ float wsm[16384];
    const float* W;
    switch (blockIdx.x) {
        case 0: W = w0; break; case 1: W = w1; break; case 2: W = w2; break;
        case 3: W = w3; break; case 4: W = w4; break; case 5: W = w5; break;
        case 6: W = w6; break; case 7: W = w7; break; default: W = w8; break;
    }
    const int tid = threadIdx.x;
    for (int i = tid; i < 16384; i += PACK_BDIM) wsm[i] = W[i];
    __syncthreads();
    unsigned short* dst = wp + (size_t)blockIdx.x * 32768;
    for (int item = tid; item < 4096; item += PACK_BDIM) {
        const int lane = item & 63, q = item >> 6;     // q = s*32 + c*8 + f
        const int s = q >> 5, cf = q & 31, c = cf >> 3, f = cf & 7;
        const int k0 = c * 32 + (lane >> 4) * 8;
        const int n  = f * 16 + (lane & 15);
        unsigned v2[4];
        for (int i2 = 0; i2 < 4; i2++) {
            unsigned short lohi[2];
            for (int t = 0; t < 2; t++) {
                float x = wsm[(k0 + i2 * 2 + t) * 128 + n];
                unsigned short hb = f2b(x);
                if (s) { hb = (unsigned short)(__float_as_uint(x - b2f(hb)) >> 16); }
                lohi[t] = hb;
            }
            v2[i2] = (unsigned)lohi[0] | ((unsigned)lohi[1] << 16);
        }
        u32x4 vv; vv[0] = v2[0]; vv[1] = v2[1]; vv[2] = v2[2]; vv[3] = v2[3];
        *(u32x4*)(dst + (size_t)(s * 32 + cf) * 512 + lane * 8) = vv;
    }
}

// Fused dual-input GRU cell. grid = B/64, 512 thr (8 waves = 4 rowgrp x 2
// colgrp; each wave 16 rows x 64 cols, 4 frags/set).
// LDS = 2 x 32KB double-buffered weight stages (buf0 = hi units, buf1 = lo
// units; 2 blocks x 64KB = 131072 B = the full pool, R2-proven co-resident).
// 18 stage-units, each prefetched one compute-unit ahead -> the barrier's
// vmcnt drain waits on loads that had a whole MFMA stretch to complete.
// amdgpu_waves_per_eu(4) budgets TOTAL regs (arch+acc, unified RF) to 128 ->
// 16 waves/CU -> 2 blocks co-resident (R5's 104-arch + hidden AGPRs = 1 blk).
// Truncation split: ah = a>>16, al = trunc(a - (a & 0xffff0000)); 3-term
// residual ~2^-15.5, well under bf16-single.
// gemm ids: 0 ir, 1 iz, 2 in_, 3 sr, 4 sz, 5 sn, 6 hr, 7 hz, 8 hn.
__global__ __launch_bounds__(BDIM) __attribute__((amdgpu_waves_per_eu(4)))
void gru_fused(
    const float* __restrict__ inp, const float* __restrict__ seqp,
    const float* __restrict__ hid, const unsigned short* __restrict__ wp,
    const float* __restrict__ b_ir, const float* __restrict__ b_iz,
    const float* __restrict__ b_in, const float* __restrict__ b_sr,
    const float* __restrict__ b_sz, const float* __restrict__ b_sn,
    const float* __restrict__ b_hr, const float* __restrict__ b_hz,
    const float* __restrict__ b_hn, float* __restrict__ outp)
{
    __shared__ __align__(16) unsigned short wbuf[2][16384]; // 2 x 32 KiB
    float* tb = (float*)wbuf[1];   // transpose overlay on buf1 (free at use sites)

    const int tid    = threadIdx.x;
    const int lane   = tid & 63;
    const int wid    = tid >> 6;       // 0..7
    const int rowgrp = wid >> 1;       // 0..3
    const int colgrp = wid & 1;        // 0..1
    const int agrp   = lane >> 4;      // 0..3 (K-group for A/B, row-group for C)
    const int a16    = lane & 15;      // M for A, N for B, col for C
    const int ncol0  = colgrp * 64;
    const size_t row0 = (size_t)blockIdx.x * 64;
    const int locrow_a = rowgrp * 16 + a16;
    const int rswA = (locrow_a & 7) << 3;

    const float* pAin  = inp  + (row0 + locrow_a) * 128;
    const float* pAseq = seqp + (row0 + locrow_a) * 128;
    const float* pAhid = hid  + (row0 + locrow_a) * 128;

    f32x4 hx[4], t[4], s1[4], nacc[4], rA[8];
    bf16x8 ahs[4];
    const f32x4 zv = {0.f, 0.f, 0.f, 0.f};

    auto stageu = [&](int g, int s, int b) {   // issue 32KB sub-stage, no wait
        const char* src = (const char*)wp + (size_t)g * 65536 + (size_t)s * 32768;
        char* dstb = (char*)wbuf[b];
        #pragma unroll
        for (int j = 0; j < 4; j++) {
            const int off = (j * 8 + wid) * 1024;  // wave-uniform LDS base
            gload_lds16(src + off + lane * 16, dstb + off);
        }
    };

    // hi unit: load A, trunc-split, acc += Ah*Wh + Al*Wh (W from buf0)
    auto hiU = [&](f32x4* acc, const float* pA, const f32x4* rAv, bool init) {
        bf16x8 al[4];
        #pragma unroll
        for (int c = 0; c < 4; c++) {
            const float* p = pA + c * 32 + agrp * 8;
            f32x4 x0 = *(const f32x4*)(p);
            f32x4 x1 = *(const f32x4*)(p + 4);
            if (rAv) { x0 *= rAv[2 * c]; x1 *= rAv[2 * c + 1]; }
            #pragma unroll
            for (int i = 0; i < 4; i++) {
                unsigned u0 = __float_as_uint(x0[i]);
                ahs[c][i] = (short)(u0 >> 16);
                float h0 = __uint_as_float(u0 & 0xffff0000u);
                al[c][i] = (short)(__float_as_uint(x0[i] - h0) >> 16);
                unsigned u1 = __float_as_uint(x1[i]);
                ahs[c][4 + i] = (short)(u1 >> 16);
                float h1 = __uint_as_float(u1 & 0xffff0000u);
                al[c][4 + i] = (short)(__float_as_uint(x1[i] - h1) >> 16);
            }
        }
        if (init) {
            #pragma unroll
            for (int f = 0; f < 4; f++) acc[f] = zv;
        }
        const unsigned short* wb = wbuf[0];
        #pragma unroll
        for (int c = 0; c < 4; c++)
            #pragma unroll
            for (int f = 0; f < 4; f++) {
                const int fglob = colgrp * 4 + f;
                const bf16x8 wh = *(const bf16x8*)(&wb[(size_t)(c * 8 + fglob) * 512 + lane * 8]);
                acc[f] = __builtin_amdgcn_mfma_f32_16x16x32_bf16(ahs[c], wh, acc[f], 0, 0, 0);
                acc[f] = __builtin_amdgcn_mfma_f32_16x16x32_bf16(al[c], wh, acc[f], 0, 0, 0);
            }
    };

    // lo unit: acc += Ah*Wl (W from buf1; ahs carried from hi unit)
    auto loU = [&](f32x4* acc) {
        const unsigned short* wb = wbuf[1];
        #pragma unroll
        for (int c = 0; c < 4; c++)
            #pragma unroll
            for (int f = 0; f < 4; f++) {
                const int fglob = colgrp * 4 + f;
                const bf16x8 wl = *(const bf16x8*)(&wb[(size_t)(c * 8 + fglob) * 512 + lane * 8]);
                acc[f] = __builtin_amdgcn_mfma_f32_16x16x32_bf16(ahs[c], wl, acc[f], 0, 0, 0);
            }
    };

    auto addb = [&](f32x4* acc, const float* b) {
        #pragma unroll
        for (int f = 0; f < 4; f++) {
            float bv = b[ncol0 + f * 16 + a16];
            #pragma unroll
            for (int j = 0; j < 4; j++) acc[f][j] += bv;
        }
    };

    auto sigm = [](float x) { return 1.f / (1.f + __expf(-x)); };
    auto tanh_ = [](float x) {
        x = fminf(18.f, fmaxf(-18.f, x));
        float e = __expf(2.f * x);
        return (e - 1.f) / (e + 1.f);
    };

    // unit order: u0(6,h) u1(6,l) u2(0,h) u3(0,l) u4(3,h) u5(3,l)
    //             u6(8,h) u7(8,l) u8(2,h) u9(2,l) u10(5,h) u11(5,l)
    //             u12(7,h) u13(7,l) u14(1,h) u15(1,l) u16(4,h) u17(4,l)
    stageu(6, 0, 0);                                  // prologue: u0 -> buf0

    // ---- hr ----
    __syncthreads(); stageu(6, 1, 1);
    hiU(hx, pAhid, nullptr, true);
    __syncthreads(); stageu(0, 0, 0);
    loU(hx); addb(hx, b_hr);
    // ---- ir ----
    __syncthreads(); stageu(0, 1, 1);
    hiU(t, pAin, nullptr, true);
    __syncthreads(); stageu(3, 0, 0);
    loU(t); addb(t, b_ir);
    #pragma unroll
    for (int f = 0; f < 4; f++)
        #pragma unroll
        for (int j = 0; j < 4; j++) s1[f][j] = sigm(t[f][j] + hx[f][j]);   // r_input
    // ---- sr ----
    __syncthreads(); stageu(3, 1, 1);
    hiU(t, pAseq, nullptr, true);
    __syncthreads(); stageu(8, 0, 0);                 // prefetch hn-hi -> buf0
    loU(t); addb(t, b_sr);

    // ---- r transpose through buf1 (u5 done), into rA registers ----
    __syncthreads();
    #pragma unroll
    for (int f = 0; f < 4; f++)
        #pragma unroll
        for (int j = 0; j < 4; j++) {
            int row = rowgrp * 16 + agrp * 4 + j;     // C-layout local row
            int col = ncol0 + f * 16 + a16;
            tb[row * 128 + (col ^ ((row & 7) << 3))] =
                0.5f * (s1[f][j] + sigm(t[f][j] + hx[f][j]));
        }
    __syncthreads();
    #pragma unroll
    for (int c = 0; c < 4; c++) {                     // r -> A-layout regs
        int rk = (c * 32 + agrp * 8) ^ rswA;
        rA[2 * c]     = *(const f32x4*)(&tb[locrow_a * 128 + rk]);
        rA[2 * c + 1] = *(const f32x4*)(&tb[locrow_a * 128 + rk + 4]);
    }

    // ---- hn ----
    __syncthreads(); stageu(8, 1, 1);                 // safe: rA reads pre-barrier
    hiU(nacc, pAhid, rA, true);
    __syncthreads(); stageu(2, 0, 0);
    loU(nacc); addb(nacc, b_hn);
    // ---- in_ ----
    __syncthreads(); stageu(2, 1, 1);
    hiU(nacc, pAin, nullptr, false);
    __syncthreads(); stageu(5, 0, 0);
    loU(nacc); addb(nacc, b_in);
    // ---- sn ----
    __syncthreads(); stageu(5, 1, 1);
    hiU(nacc, pAseq, nullptr, false);
    __syncthreads(); stageu(7, 0, 0);
    loU(nacc); addb(nacc, b_sn);
    // ---- hz ----
    __syncthreads(); stageu(7, 1, 1);
    hiU(hx, pAhid, nullptr, true);
    __syncthreads(); stageu(1, 0, 0);
    loU(hx); addb(hx, b_hz);
    // ---- iz ----
    __syncthreads(); stageu(1, 1, 1);
    hiU(t, pAin, nullptr, true);
    __syncthreads(); stageu(4, 0, 0);
    loU(t); addb(t, b_iz);
    #pragma unroll
    for (int f = 0; f < 4; f++)
        #pragma unroll
        for (int j = 0; j < 4; j++) s1[f][j] = sigm(t[f][j] + hx[f][j]);   // z_input
    // ---- sz ----
    __syncthreads(); stageu(4, 1, 1);
    hiU(t, pAseq, nullptr, true);
    __syncthreads();                                  // last unit: no prefetch
    loU(t); addb(t, b_sz);

    // ---- blend in frag space -> buf1 -> coalesced store ----
    __syncthreads();
    #pragma unroll
    for (int f = 0; f < 4; f++)
        #pragma unroll
        for (int j = 0; j < 4; j++) {
            int row = rowgrp * 16 + agrp * 4 + j;
            int col = ncol0 + f * 16 + a16;
            float zz = 0.5f * (s1[f][j] + sigm(t[f][j] + hx[f][j]));
            float h  = hid[(row0 + row) * 128 + col]; // frag-direct, L2-warm
            float nn = tanh_(nacc[f][j]);
            tb[row * 128 + (col ^ ((row & 7) << 3))] = (1.f - zz) * nn + zz * h;
        }
    __syncthreads();
    #pragma unroll
    for (int p = 0; p < 4; p++) {
        int e = p * 2048 + tid * 4;
        int rrow = e >> 7, c0 = e & 127;
        f32x4 v = *(const f32x4*)(&tb[rrow * 128 + (c0 ^ ((rrow & 7) << 3))]);
        *(f32x4*)(&outp[(row0 + rrow) * 128 + c0]) = v;
    }
}

extern "C" void kernel_launch(void* const* d_in, const int* in_sizes, int n_in,
                              void* d_out, int out_size, void* d_ws, size_t ws_size,
                              hipStream_t stream)
{
    (void)in_sizes; (void)n_in; (void)out_size; (void)ws_size;
    const float* inp  = (const float*)d_in[0];
    const float* seqp = (const float*)d_in[1];
    const float* hid  = (const float*)d_in[2];
    const float* W[9]; const float* Bv[9];
    for (int i = 0; i < 9; i++) {
        W[i]  = (const float*)d_in[3 + 2 * i];
        Bv[i] = (const float*)d_in[4 + 2 * i];
    }
    unsigned short* wp = (unsigned short*)d_ws; // needs 589,824 B

    pack_weights<<<9, PACK_BDIM, 0, stream>>>(W[0], W[1], W[2], W[3], W[4],
                                              W[5], W[6], W[7], W[8], wp);
    gru_fused<<<2048, BDIM, 0, stream>>>(inp, seqp, hid, wp,
                                         Bv[0], Bv[1], Bv[2], Bv[3], Bv[4],
                                         Bv[5], Bv[6], Bv[7], Bv[8],
                                         (float*)d_out);
}